// Round 1
// 405.964 us; speedup vs baseline: 1.0833x; 1.0833x over previous
//
#include <hip/hip_runtime.h>
#include <hip/hip_bf16.h>

// Problem constants
#define DIM    256
#define NWIN   294            // tokens per window = 6*7*7
#define BWIN   288            // windows = 2*12*12
#define MROWS  (BWIN * NWIN)  // 84672 total tokens
#define MPAD   84736          // 662 * 128 (M padded for 128-row tiles)
#define NHEADS 8
#define DH     32
#define NBIAS  1859           // 11*13*13
#define QPAD   304            // padded query/key dim for dense bias table

typedef __attribute__((ext_vector_type(8))) short  short8;  // 8 bf16 = 4 VGPRs
typedef __attribute__((ext_vector_type(4))) float  f32x4;

__device__ __forceinline__ unsigned short f2bf(float f) {
    unsigned int u = __float_as_uint(f);
    u += 0x7FFFu + ((u >> 16) & 1u);     // round-to-nearest-even
    return (unsigned short)(u >> 16);
}

__device__ __forceinline__ unsigned pk2bf(float a, float b) {
    __hip_bfloat162 h = __float22bfloat162_rn(float2{a, b});  // v_cvt_pk_bf16_f32
    unsigned u;
    __builtin_memcpy(&u, &h, 4);
    return u;
}

// async global->LDS, 16B per lane. LDS dest = wave-uniform base + lane*16.
__device__ __forceinline__ void gl_lds16(const void* g, void* l) {
    __builtin_amdgcn_global_load_lds((const __attribute__((address_space(1))) unsigned int*)g,
                                     (__attribute__((address_space(3))) unsigned int*)l,
                                     16, 0, 0);
}

// ---------------------------------------------------------------------------
// Prep A: gather + cast x -> Xb bf16 (MPAD x 256) row-major in (B*n, d) order.
// ---------------------------------------------------------------------------
__global__ __launch_bounds__(256) void prep_x(const float* __restrict__ x,
                                              unsigned short* __restrict__ Xb)
{
    const int g   = blockIdx.x * 256 + threadIdx.x;
    const int row = g >> 5;
    const int col = (g & 31) * 8;
    if (row >= MPAD) return;
    uint4 pk;
    if (row < MROWS) {
        const int bw = row / NWIN, rw = row - bw * NWIN;
        const int bb = bw / 144,  r2 = bw - bb * 144;
        const int gxi = r2 / 12,  gyi = r2 - gxi * 12;
        const int lz = rw / 49,   r3 = rw - lz * 49;
        const int wa = r3 / 7,    wb = r3 - wa * 7;
        const float* src = x + ((((((size_t)bb * 6 + lz) * 12 + gxi) * 12 + gyi) * 7 + wa) * 7 + wb) * DIM + col;
        const float4 f0 = *(const float4*)(src);
        const float4 f1 = *(const float4*)(src + 4);
        pk.x = pk2bf(f0.x, f0.y);
        pk.y = pk2bf(f0.z, f0.w);
        pk.z = pk2bf(f1.x, f1.y);
        pk.w = pk2bf(f1.z, f1.w);
    } else {
        pk = (uint4){0u, 0u, 0u, 0u};
    }
    *(uint4*)(Xb + (size_t)row * 256 + col) = pk;
}

// ---------------------------------------------------------------------------
// Prep B: cast + transpose weights to (N,K) bf16.
// ---------------------------------------------------------------------------
__global__ __launch_bounds__(256) void prep_w(const float* __restrict__ Wq,
                                              const float* __restrict__ Wkv,
                                              const float* __restrict__ Wout,
                                              unsigned short* __restrict__ Wt,
                                              unsigned short* __restrict__ Wot)
{
    const int g = blockIdx.x * 256 + threadIdx.x;
    if (g < 768 * 256) {
        const int n = g >> 8, k = g & 255;
        const float v = (n < 256) ? Wq[k * 256 + n] : Wkv[k * 512 + (n - 256)];
        Wt[g] = f2bf(v);
    } else {
        const int g2 = g - 768 * 256;
        const int n = g2 >> 8, k = g2 & 255;
        Wot[g2] = f2bf(Wout[k * 256 + n]);
    }
}

// ---------------------------------------------------------------------------
// Prep C: dense per-head bias table biasT[h][q][k] (QPAD x QPAD), pre-scaled
// by log2(e). Pad entries (q>=294 or k>=294) = 0. 3 MB -> L2-resident.
// ---------------------------------------------------------------------------
__global__ __launch_bounds__(256) void prep_bias(const float* __restrict__ bias_table,
                                                 float* __restrict__ biasT)
{
    const int g = blockIdx.x * 256 + threadIdx.x;
    if (g >= NHEADS * QPAD * QPAD) return;
    const int k = g % QPAD;
    const int q = (g / QPAD) % QPAD;
    const int h = g / (QPAD * QPAD);
    float v = 0.f;
    if (q < NWIN && k < NWIN) {
        const int ql = q / 49, qr = q - ql * 49, qa = qr / 7, qb = qr - qa * 7;
        const int kl = k / 49, kr = k - kl * 49, ka = kr / 7, kb = kr - ka * 7;
        const int idx = 169 * (ql - kl + 5) + 13 * (qa - ka + 6) + (qb - kb + 6);
        v = bias_table[idx * NHEADS + h] * 1.44269504088896f;
    }
    biasT[g] = v;
}

// ---------------------------------------------------------------------------
// Kernel 1: QKV projection, bf16 MFMA (m97 structure). Unchanged.
// ---------------------------------------------------------------------------
__global__ __launch_bounds__(256) void gemm_qkv(
    const unsigned short* __restrict__ Xb, const unsigned short* __restrict__ Wt,
    const float* __restrict__ bq, const float* __restrict__ bkv,
    unsigned short* __restrict__ Qb, unsigned short* __restrict__ Kb,
    unsigned short* __restrict__ Vtb)
{
    __shared__ __align__(16) unsigned short As[128 * 64];
    __shared__ __align__(16) unsigned short Bs[128 * 64];

    const int bn = blockIdx.x % 6;
    const int bm = blockIdx.x / 6;
    const int tileM = bm * 128;
    const int tileN = bn * 128;

    const int t    = threadIdx.x;
    const int w    = t >> 6;
    const int lane = t & 63;
    const int quad = lane >> 4;
    const int l15  = lane & 15;
    const int wm   = w >> 1, wn = w & 1;

    const int rA = lane >> 3;
    const int kA = (lane & 7) * 8;
    const unsigned short* aBase = Xb + ((size_t)tileM + rA) * 256 + kA;
    const unsigned short* bBase = Wt + ((size_t)tileN + rA) * 256 + kA;

    f32x4 acc[4][4] = {};

    for (int kb = 0; kb < 4; ++kb) {
        const int k0 = kb * 64;
        __syncthreads();
#pragma unroll
        for (int i = 0; i < 4; ++i) {
            const int c = w * 4 + i;
            gl_lds16(aBase + (size_t)c * 8 * 256 + k0, &As[c * 512]);
            gl_lds16(bBase + (size_t)c * 8 * 256 + k0, &Bs[c * 512]);
        }
        __syncthreads();
#pragma unroll
        for (int c2 = 0; c2 < 2; ++c2) {
            const int kk = c2 * 32 + quad * 8;
            short8 a[4], b[4];
#pragma unroll
            for (int mi = 0; mi < 4; ++mi)
                a[mi] = *(const short8*)&As[(wm * 64 + mi * 16 + l15) * 64 + kk];
#pragma unroll
            for (int ni = 0; ni < 4; ++ni)
                b[ni] = *(const short8*)&Bs[(wn * 64 + ni * 16 + l15) * 64 + kk];
#pragma unroll
            for (int mi = 0; mi < 4; ++mi)
#pragma unroll
                for (int ni = 0; ni < 4; ++ni)
                    acc[mi][ni] = __builtin_amdgcn_mfma_f32_16x16x32_bf16(a[mi], b[ni], acc[mi][ni], 0, 0, 0);
        }
    }

    const int colB = tileN + wn * 64;
    float bias[4];
#pragma unroll
    for (int ni = 0; ni < 4; ++ni) {
        const int n = colB + ni * 16 + l15;
        bias[ni] = (n < 256) ? bq[n] : bkv[n - 256];
    }
    const int rowB = tileM + wm * 64 + quad * 4;
#pragma unroll
    for (int mi = 0; mi < 4; ++mi) {
#pragma unroll
        for (int r = 0; r < 4; ++r) {
            const int row = rowB + mi * 16 + r;
            if (row < MROWS) {
                const int bw = row / NWIN;
                const int rw = row - bw * NWIN;
#pragma unroll
                for (int ni = 0; ni < 4; ++ni) {
                    const int n = colB + ni * 16 + l15;
                    const unsigned short v = f2bf(acc[mi][ni][r] + bias[ni]);
                    const int ch = n & 255;
                    const int hd = ch >> 5, di = ch & 31;
                    if (n < 512) {
                        unsigned short* dst = (n < 256) ? Qb : Kb;
                        dst[((size_t)(bw * NHEADS + hd) * NWIN + rw) * DH + di] = v;
                    } else {
                        Vtb[((size_t)(bw * NHEADS + hd) * DH + di) * NWIN + rw] = v;
                    }
                }
            }
        }
    }
}

// ---------------------------------------------------------------------------
// Kernel 2: MFMA flash attention, S^T formulation.
//   S^T = K Q^T -> exp2 with fused bias (dense biasT from L2, no LDS gather)
//   -> PV with PERMUTED key order: lane (quad,l15) already holds the A-frag
//      {keys quad*4+0..3 of halves 0,1} for query l15 -> zero shuffles.
//      V staged in matching permuted order: pos p = kt*32+quad*8+half*4+j
//      <-> key kt*32+half*16+quad*4+j.
// ---------------------------------------------------------------------------
__global__ __launch_bounds__(256, 3) void attn_kernel(
    const unsigned short* __restrict__ Qb, const unsigned short* __restrict__ Kb,
    const unsigned short* __restrict__ Vtb, const float* __restrict__ biasT,
    unsigned short* __restrict__ Ob)
{
    const int bh   = blockIdx.x;      // 0..2303
    const int bwin = bh >> 3;
    const int h    = bh & 7;

    __shared__ __align__(16) unsigned short Ks[304 * 40];   // 24320 B, pitch 40 halves
    __shared__ __align__(16) unsigned short Vts[32 * 328];  // 20992 B, permuted V^T, pitch 328

    const int t    = threadIdx.x;
    const int w    = t >> 6;
    const int lane = t & 63;
    const int quad = lane >> 4;
    const int l15  = lane & 15;

    // ---- stage K with padded pitch (rows >= NWIN zeroed)
    {
        const unsigned short* Kg = Kb + (size_t)bh * (NWIN * DH);
        for (int i = t; i < 304 * 4; i += 256) {
            const int row = i >> 2, seg = i & 3;
            uint4 v = (uint4){0u, 0u, 0u, 0u};
            if (row < NWIN) v = *(const uint4*)(Kg + row * 32 + seg * 8);
            *(uint4*)(Ks + row * 40 + seg * 8) = v;
        }
    }
    // ---- stage V^T in permuted key order, zero pad (8B chunks)
    {
        const unsigned short* Vg = Vtb + (size_t)bh * (DH * NWIN);
        for (int i = t; i < 32 * 80; i += 256) {
            const int d = i / 80, c = i - d * 80;     // c: 8B chunk = 4 positions
            const int kt = c >> 3, qd = (c >> 1) & 3, hf = c & 1;
            const int kb = kt * 32 + hf * 16 + qd * 4;  // source key base
            unsigned int u0 = 0u, u1 = 0u;
            if (kb + 3 < NWIN) {
                u0 = *(const unsigned int*)(Vg + d * NWIN + kb);
                u1 = *(const unsigned int*)(Vg + d * NWIN + kb + 2);
            } else if (kb < NWIN) {   // boundary chunk (keys 292,293)
                unsigned short r0 = Vg[d * NWIN + kb];
                unsigned short r1 = (kb + 1 < NWIN) ? Vg[d * NWIN + kb + 1] : (unsigned short)0;
                unsigned short r2 = (kb + 2 < NWIN) ? Vg[d * NWIN + kb + 2] : (unsigned short)0;
                u0 = (unsigned int)r0 | ((unsigned int)r1 << 16);
                u1 = (unsigned int)r2;
            }
            unsigned int* dst = (unsigned int*)(Vts + d * 328 + c * 4);
            dst[0] = u0; dst[1] = u1;
        }
    }
    __syncthreads();

    const float SL2E = 0.25503486f;   // (1/sqrt(32)) * log2(e)
    const unsigned short* Qg = Qb + (size_t)bh * (NWIN * DH);
    const float* biasH = biasT + (size_t)h * QPAD * QPAD;
    const short8 ones = (short8){0x3F80,0x3F80,0x3F80,0x3F80,0x3F80,0x3F80,0x3F80,0x3F80};

#pragma unroll
    for (int r5 = 0; r5 < 5; ++r5) {
        const int it = 4 * r5 + w;
        if (it < 19) {
            // ---- Q fragment for this query tile (B-operand; zero pad rows)
            short8 qf;
            const int qrow = it * 16 + l15;
            if (qrow < NWIN) qf = *(const short8*)(Qg + qrow * DH + quad * 8);
            else             qf = (short8){0,0,0,0,0,0,0,0};

            const float* bb = biasH + (size_t)qrow * QPAD;  // bias row for query qrow

            // ---- S^T = K Q^T : D(row=key quad*4+reg, col=query l15)
            f32x4 S[19];
#pragma unroll
            for (int jt = 0; jt < 19; ++jt) {
                const short8 kf = *(const short8*)(Ks + (jt * 16 + l15) * 40 + quad * 8);
                S[jt] = __builtin_amdgcn_mfma_f32_16x16x32_bf16(kf, qf, (f32x4){0.f,0.f,0.f,0.f}, 0, 0, 0);
            }

            // ---- p = exp2(s*SL2E + bias'); bias from dense L2-resident table
            unsigned pk0[20], pk1[20];
            pk0[19] = 0u; pk1[19] = 0u;
#pragma unroll
            for (int jt = 0; jt < 19; ++jt) {
                const f32x4 b4 = *(const f32x4*)(bb + jt * 16 + quad * 4);
                float p0 = exp2f(fmaf(S[jt][0], SL2E, b4[0]));
                float p1 = exp2f(fmaf(S[jt][1], SL2E, b4[1]));
                float p2 = exp2f(fmaf(S[jt][2], SL2E, b4[2]));
                float p3 = exp2f(fmaf(S[jt][3], SL2E, b4[3]));
                if (jt == 18) {     // mask pad keys (288 + quad*4 + r >= 294)
                    if (quad * 4 + 0 >= 6) p0 = 0.f;
                    if (quad * 4 + 1 >= 6) p1 = 0.f;
                    if (quad * 4 + 2 >= 6) p2 = 0.f;
                    if (quad * 4 + 3 >= 6) p3 = 0.f;
                }
                pk0[jt] = pk2bf(p0, p1);
                pk1[jt] = pk2bf(p2, p3);
            }

            // ---- O = P V, lsum = P 1. A-fragment is a pure register repack:
            // k-slot order p = quad*8 + half*4 + j <-> key = half*16+quad*4+j,
            // matching Vts' permuted staging. No cross-lane movement needed.
            f32x4 o0 = {0.f,0.f,0.f,0.f}, o1 = {0.f,0.f,0.f,0.f}, o2 = {0.f,0.f,0.f,0.f};
#pragma unroll
            for (int kt = 0; kt < 10; ++kt) {
                uint4 pw;
                pw.x = pk0[2 * kt];       // keys quad*4+0,1 (half 0)
                pw.y = pk1[2 * kt];       // keys quad*4+2,3 (half 0)
                pw.z = pk0[2 * kt + 1];   // keys 16+quad*4+0,1 (half 1)
                pw.w = pk1[2 * kt + 1];   // keys 16+quad*4+2,3 (half 1)
                short8 pa;
                __builtin_memcpy(&pa, &pw, 16);
                const short8 v0 = *(const short8*)(Vts + l15 * 328 + kt * 32 + quad * 8);
                const short8 v1 = *(const short8*)(Vts + (16 + l15) * 328 + kt * 32 + quad * 8);
                o0 = __builtin_amdgcn_mfma_f32_16x16x32_bf16(pa, v0, o0, 0, 0, 0);
                o1 = __builtin_amdgcn_mfma_f32_16x16x32_bf16(pa, v1, o1, 0, 0, 0);
                o2 = __builtin_amdgcn_mfma_f32_16x16x32_bf16(pa, ones, o2, 0, 0, 0);
            }

            // ---- normalize + store bf16 (row=query=quad*4+r, col d = l15 / 16+l15)
#pragma unroll
            for (int r = 0; r < 4; ++r) {
                const int rg = it * 16 + quad * 4 + r;
                if (rg < NWIN) {
                    const float inv = 1.0f / o2[r];
                    unsigned short* op = Ob + ((size_t)bwin * NWIN + rg) * DIM + h * DH;
                    op[l15]      = f2bf(o0[r] * inv);
                    op[16 + l15] = f2bf(o1[r] * inv);
                }
            }
        }
    }
}

// ---------------------------------------------------------------------------
// Kernel 3: output projection, bf16 MFMA + fp32 scatter. Unchanged.
// ---------------------------------------------------------------------------
__global__ __launch_bounds__(256) void gemm_out(
    const unsigned short* __restrict__ Ob, const unsigned short* __restrict__ Wot,
    float* __restrict__ out)
{
    __shared__ __align__(16) unsigned short As[128 * 64];
    __shared__ __align__(16) unsigned short Bs[128 * 64];

    const int bn = blockIdx.x & 1;
    const int bm = blockIdx.x >> 1;
    const int tileM = bm * 128;
    const int tileN = bn * 128;

    const int t    = threadIdx.x;
    const int w    = t >> 6;
    const int lane = t & 63;
    const int quad = lane >> 4;
    const int l15  = lane & 15;
    const int wm   = w >> 1, wn = w & 1;

    const int rA = lane >> 3;
    const int kA = (lane & 7) * 8;
    const unsigned short* aBase = Ob  + ((size_t)tileM + rA) * 256 + kA;
    const unsigned short* bBase = Wot + ((size_t)tileN + rA) * 256 + kA;

    f32x4 acc[4][4] = {};

    for (int kb = 0; kb < 4; ++kb) {
        const int k0 = kb * 64;
        __syncthreads();
#pragma unroll
        for (int i = 0; i < 4; ++i) {
            const int c = w * 4 + i;
            gl_lds16(aBase + (size_t)c * 8 * 256 + k0, &As[c * 512]);
            gl_lds16(bBase + (size_t)c * 8 * 256 + k0, &Bs[c * 512]);
        }
        __syncthreads();
#pragma unroll
        for (int c2 = 0; c2 < 2; ++c2) {
            const int kk = c2 * 32 + quad * 8;
            short8 a[4], b[4];
#pragma unroll
            for (int mi = 0; mi < 4; ++mi)
                a[mi] = *(const short8*)&As[(wm * 64 + mi * 16 + l15) * 64 + kk];
#pragma unroll
            for (int ni = 0; ni < 4; ++ni)
                b[ni] = *(const short8*)&Bs[(wn * 64 + ni * 16 + l15) * 64 + kk];
#pragma unroll
            for (int mi = 0; mi < 4; ++mi)
#pragma unroll
                for (int ni = 0; ni < 4; ++ni)
                    acc[mi][ni] = __builtin_amdgcn_mfma_f32_16x16x32_bf16(a[mi], b[ni], acc[mi][ni], 0, 0, 0);
        }
    }

    const int colB = tileN + wn * 64;
    const int rowB = tileM + wm * 64 + quad * 4;
#pragma unroll
    for (int mi = 0; mi < 4; ++mi) {
#pragma unroll
        for (int r = 0; r < 4; ++r) {
            const int row = rowB + mi * 16 + r;
            if (row < MROWS) {
                const int bw = row / NWIN, rw = row - bw * NWIN;
                const int bb = bw / 144,  r2 = bw - bb * 144;
                const int gxi = r2 / 12,  gyi = r2 - gxi * 12;
                const int lz = rw / 49,   r3 = rw - lz * 49;
                const int wa = r3 / 7,    wb = r3 - wa * 7;
                float* orow = out + ((((((size_t)bb * 6 + lz) * 12 + gxi) * 12 + gyi) * 7 + wa) * 7 + wb) * DIM;
#pragma unroll
                for (int ni = 0; ni < 4; ++ni)
                    orow[colB + ni * 16 + l15] = acc[mi][ni][r];
            }
        }
    }
}

// ---------------------------------------------------------------------------
extern "C" void kernel_launch(void* const* d_in, const int* in_sizes, int n_in,
                              void* d_out, int out_size, void* d_ws, size_t ws_size,
                              hipStream_t stream)
{
    const float* x          = (const float*)d_in[0];
    const float* Wq         = (const float*)d_in[1];
    const float* bq         = (const float*)d_in[2];
    const float* Wkv        = (const float*)d_in[3];
    const float* bkv        = (const float*)d_in[4];
    const float* Wout       = (const float*)d_in[5];
    const float* bias_table = (const float*)d_in[6];
    float* out = (float*)d_out;

    const size_t planePad = (size_t)MPAD * DIM;
    const size_t plane    = (size_t)MROWS * DIM;
    unsigned short* Xb  = (unsigned short*)d_ws;
    unsigned short* Qb  = Xb + planePad;
    unsigned short* Kb  = Qb + plane;
    unsigned short* Vtb = Kb + plane;
    unsigned short* Ob  = Vtb + plane;
    unsigned short* Wt  = Ob + planePad;
    unsigned short* Wot = Wt + 768 * 256;
    float*          biasT = (float*)(Wot + 256 * 256);   // 16B-aligned (all prior sizes are multiples of 8 halves)

    prep_x<<<MPAD / 8, 256, 0, stream>>>(x, Xb);
    prep_w<<<1024, 256, 0, stream>>>(Wq, Wkv, Wout, Wt, Wot);
    prep_bias<<<(NHEADS * QPAD * QPAD + 255) / 256, 256, 0, stream>>>(bias_table, biasT);
    gemm_qkv<<<662 * 6, 256, 0, stream>>>(Xb, Wt, bq, bkv, Qb, Kb, Vtb);
    attn_kernel<<<BWIN * NHEADS, 256, 0, stream>>>(Qb, Kb, Vtb, biasT, Ob);
    gemm_out<<<662 * 2, 256, 0, stream>>>(Ob, Wot, out);
}

// Round 2
// 375.210 us; speedup vs baseline: 1.1721x; 1.0820x over previous
//
#include <hip/hip_runtime.h>
#include <hip/hip_bf16.h>

// Problem constants
#define DIM    256
#define NWIN   294            // tokens per window = 6*7*7
#define BWIN   288            // windows = 2*12*12
#define MROWS  (BWIN * NWIN)  // 84672 total tokens
#define MPAD   84736          // 662 * 128 (M padded for 128-row tiles)
#define NHEADS 8
#define DH     32
#define NBIAS  1859           // 11*13*13
#define QPAD   304            // padded query/key dim for dense bias table

typedef __attribute__((ext_vector_type(8))) short  short8;  // 8 bf16 = 4 VGPRs
typedef __attribute__((ext_vector_type(4))) float  f32x4;

__device__ __forceinline__ unsigned short f2bf(float f) {
    unsigned int u = __float_as_uint(f);
    u += 0x7FFFu + ((u >> 16) & 1u);     // round-to-nearest-even
    return (unsigned short)(u >> 16);
}

__device__ __forceinline__ unsigned pk2bf(float a, float b) {
    __hip_bfloat162 h = __float22bfloat162_rn(float2{a, b});  // v_cvt_pk_bf16_f32
    unsigned u;
    __builtin_memcpy(&u, &h, 4);
    return u;
}

// async global->LDS, 16B per lane. LDS dest = wave-uniform base + lane*16.
__device__ __forceinline__ void gl_lds16(const void* g, void* l) {
    __builtin_amdgcn_global_load_lds((const __attribute__((address_space(1))) unsigned int*)g,
                                     (__attribute__((address_space(3))) unsigned int*)l,
                                     16, 0, 0);
}

// bijective XCD-chunked swizzle (m204): consecutive wg ranges -> one XCD.
__device__ __forceinline__ int xcd_swizzle(int orig, int nwg) {
    const int xcd = orig & 7, idx = orig >> 3;
    const int q = nwg >> 3, r = nwg & 7;
    return (xcd < r) ? (xcd * (q + 1) + idx) : (r * (q + 1) + (xcd - r) * q + idx);
}

// stage one 128x64 A-tile + B-tile half (per wave w: 4 column-groups each)
__device__ __forceinline__ void stage_tile(const unsigned short* aBase, const unsigned short* bBase,
                                           unsigned short* As_, unsigned short* Bs_, int w, int k0)
{
#pragma unroll
    for (int i = 0; i < 4; ++i) {
        const int c = w * 4 + i;
        gl_lds16(aBase + (size_t)c * 8 * 256 + k0, As_ + c * 512);
        gl_lds16(bBase + (size_t)c * 8 * 256 + k0, Bs_ + c * 512);
    }
}

// 64-deep K compute on a staged 128x64 tile pair
__device__ __forceinline__ void tile_mfma(const unsigned short* As_, const unsigned short* Bs_,
                                          int wm, int wn, int quad, int l15, f32x4 (&acc)[4][4])
{
#pragma unroll
    for (int c2 = 0; c2 < 2; ++c2) {
        const int kk = c2 * 32 + quad * 8;
        short8 a[4], b[4];
#pragma unroll
        for (int mi = 0; mi < 4; ++mi)
            a[mi] = *(const short8*)&As_[(wm * 64 + mi * 16 + l15) * 64 + kk];
#pragma unroll
        for (int ni = 0; ni < 4; ++ni)
            b[ni] = *(const short8*)&Bs_[(wn * 64 + ni * 16 + l15) * 64 + kk];
#pragma unroll
        for (int mi = 0; mi < 4; ++mi)
#pragma unroll
            for (int ni = 0; ni < 4; ++ni)
                acc[mi][ni] = __builtin_amdgcn_mfma_f32_16x16x32_bf16(a[mi], b[ni], acc[mi][ni], 0, 0, 0);
    }
}

// ---------------------------------------------------------------------------
// Prep A: gather + cast x -> Xb bf16 (MPAD x 256) row-major in (B*n, d) order.
// ---------------------------------------------------------------------------
__global__ __launch_bounds__(256) void prep_x(const float* __restrict__ x,
                                              unsigned short* __restrict__ Xb)
{
    const int g   = blockIdx.x * 256 + threadIdx.x;
    const int row = g >> 5;
    const int col = (g & 31) * 8;
    if (row >= MPAD) return;
    uint4 pk;
    if (row < MROWS) {
        const int bw = row / NWIN, rw = row - bw * NWIN;
        const int bb = bw / 144,  r2 = bw - bb * 144;
        const int gxi = r2 / 12,  gyi = r2 - gxi * 12;
        const int lz = rw / 49,   r3 = rw - lz * 49;
        const int wa = r3 / 7,    wb = r3 - wa * 7;
        const float* src = x + ((((((size_t)bb * 6 + lz) * 12 + gxi) * 12 + gyi) * 7 + wa) * 7 + wb) * DIM + col;
        const float4 f0 = *(const float4*)(src);
        const float4 f1 = *(const float4*)(src + 4);
        pk.x = pk2bf(f0.x, f0.y);
        pk.y = pk2bf(f0.z, f0.w);
        pk.z = pk2bf(f1.x, f1.y);
        pk.w = pk2bf(f1.z, f1.w);
    } else {
        pk = (uint4){0u, 0u, 0u, 0u};
    }
    *(uint4*)(Xb + (size_t)row * 256 + col) = pk;
}

// ---------------------------------------------------------------------------
// Prep B: cast + transpose weights to (N,K) bf16.
// ---------------------------------------------------------------------------
__global__ __launch_bounds__(256) void prep_w(const float* __restrict__ Wq,
                                              const float* __restrict__ Wkv,
                                              const float* __restrict__ Wout,
                                              unsigned short* __restrict__ Wt,
                                              unsigned short* __restrict__ Wot)
{
    const int g = blockIdx.x * 256 + threadIdx.x;
    if (g < 768 * 256) {
        const int n = g >> 8, k = g & 255;
        const float v = (n < 256) ? Wq[k * 256 + n] : Wkv[k * 512 + (n - 256)];
        Wt[g] = f2bf(v);
    } else {
        const int g2 = g - 768 * 256;
        const int n = g2 >> 8, k = g2 & 255;
        Wot[g2] = f2bf(Wout[k * 256 + n]);
    }
}

// ---------------------------------------------------------------------------
// Prep C: dense per-head bias table biasT[h][q][k] (QPAD x QPAD), pre-scaled
// by log2(e). Pad entries (q>=294 or k>=294) = 0. 3 MB -> L2-resident.
// ---------------------------------------------------------------------------
__global__ __launch_bounds__(256) void prep_bias(const float* __restrict__ bias_table,
                                                 float* __restrict__ biasT)
{
    const int g = blockIdx.x * 256 + threadIdx.x;
    if (g >= NHEADS * QPAD * QPAD) return;
    const int k = g % QPAD;
    const int q = (g / QPAD) % QPAD;
    const int h = g / (QPAD * QPAD);
    float v = 0.f;
    if (q < NWIN && k < NWIN) {
        const int ql = q / 49, qr = q - ql * 49, qa = qr / 7, qb = qr - qa * 7;
        const int kl = k / 49, kr = k - kl * 49, ka = kr / 7, kb = kr - ka * 7;
        const int idx = 169 * (ql - kl + 5) + 13 * (qa - ka + 6) + (qb - kb + 6);
        v = bias_table[idx * NHEADS + h] * 1.44269504088896f;
    }
    biasT[g] = v;
}

// ---------------------------------------------------------------------------
// Kernel 1: QKV projection. Double-buffered stage-ahead K-loop (T3-minimum),
// XCD-chunked block swizzle, packed V^T epilogue stores.
// ---------------------------------------------------------------------------
__global__ __launch_bounds__(256) void gemm_qkv(
    const unsigned short* __restrict__ Xb, const unsigned short* __restrict__ Wt,
    const float* __restrict__ bq, const float* __restrict__ bkv,
    unsigned short* __restrict__ Qb, unsigned short* __restrict__ Kb,
    unsigned short* __restrict__ Vtb)
{
    __shared__ __align__(16) unsigned short As[2][128 * 64];
    __shared__ __align__(16) unsigned short Bs[2][128 * 64];

    const int wg = xcd_swizzle(blockIdx.x, 662 * 6);
    const int bn = wg % 6;
    const int bm = wg / 6;
    const int tileM = bm * 128;
    const int tileN = bn * 128;

    const int t    = threadIdx.x;
    const int w    = t >> 6;
    const int lane = t & 63;
    const int quad = lane >> 4;
    const int l15  = lane & 15;
    const int wm   = w >> 1, wn = w & 1;

    const int rA = lane >> 3;
    const int kA = (lane & 7) * 8;
    const unsigned short* aBase = Xb + ((size_t)tileM + rA) * 256 + kA;
    const unsigned short* bBase = Wt + ((size_t)tileN + rA) * 256 + kA;

    f32x4 acc[4][4] = {};

    // prologue: stage tile 0
    stage_tile(aBase, bBase, As[0], Bs[0], w, 0);
    __syncthreads();
#pragma unroll
    for (int kb = 0; kb < 3; ++kb) {
        const int cur = kb & 1;
        stage_tile(aBase, bBase, As[cur ^ 1], Bs[cur ^ 1], w, (kb + 1) * 64);  // prefetch next
        tile_mfma(As[cur], Bs[cur], wm, wn, quad, l15, acc);                   // compute current
        __syncthreads();   // drains vmcnt(0): next buffer ready; lgkmcnt: reads done
    }
    tile_mfma(As[1], Bs[1], wm, wn, quad, l15, acc);                           // kb=3

    const int colB = tileN + wn * 64;
    float bias[4];
#pragma unroll
    for (int ni = 0; ni < 4; ++ni) {
        const int n = colB + ni * 16 + l15;
        bias[ni] = (n < 256) ? bq[n] : bkv[n - 256];
    }
    const int rowB = tileM + wm * 64 + quad * 4;
#pragma unroll
    for (int mi = 0; mi < 4; ++mi) {
        const int row0 = rowB + mi * 16;
        if (row0 < MROWS) {
            const int bw0 = row0 / NWIN;
            const int rw0 = row0 - bw0 * NWIN;
            const bool same = (rw0 <= NWIN - 4);   // 4 rows within one window
#pragma unroll
            for (int ni = 0; ni < 4; ++ni) {
                const int n = colB + ni * 16 + l15;
                const int ch = n & 255;
                const int hd = ch >> 5, di = ch & 31;
                if (n < 512) {
                    unsigned short* dst = (n < 256) ? Qb : Kb;
                    if (same) {
                        unsigned short* p = dst + ((size_t)(bw0 * NHEADS + hd) * NWIN + rw0) * DH + di;
#pragma unroll
                        for (int r = 0; r < 4; ++r)
                            p[r * DH] = f2bf(acc[mi][ni][r] + bias[ni]);
                    } else {
#pragma unroll
                        for (int r = 0; r < 4; ++r) {
                            const int row = row0 + r;
                            if (row < MROWS) {
                                const int bw = row / NWIN, rw = row - bw * NWIN;
                                dst[((size_t)(bw * NHEADS + hd) * NWIN + rw) * DH + di] =
                                    f2bf(acc[mi][ni][r] + bias[ni]);
                            }
                        }
                    }
                } else {
                    if (same) {
                        // rw is the fastest dim of Vtb: pack 4 rows -> 2x4B stores.
                        // rw0 is even (row0 % 4 == 0, NWIN even) -> 4B aligned.
                        unsigned short* p = Vtb + ((size_t)(bw0 * NHEADS + hd) * DH + di) * NWIN + rw0;
                        const unsigned lo = pk2bf(acc[mi][ni][0] + bias[ni], acc[mi][ni][1] + bias[ni]);
                        const unsigned hi = pk2bf(acc[mi][ni][2] + bias[ni], acc[mi][ni][3] + bias[ni]);
                        *(unsigned*)(p)     = lo;
                        *(unsigned*)(p + 2) = hi;
                    } else {
#pragma unroll
                        for (int r = 0; r < 4; ++r) {
                            const int row = row0 + r;
                            if (row < MROWS) {
                                const int bw = row / NWIN, rw = row - bw * NWIN;
                                Vtb[((size_t)(bw * NHEADS + hd) * DH + di) * NWIN + rw] =
                                    f2bf(acc[mi][ni][r] + bias[ni]);
                            }
                        }
                    }
                }
            }
        }
    }
}

// ---------------------------------------------------------------------------
// Kernel 2: MFMA flash attention, S^T formulation (unchanged from R1).
// ---------------------------------------------------------------------------
__global__ __launch_bounds__(256, 3) void attn_kernel(
    const unsigned short* __restrict__ Qb, const unsigned short* __restrict__ Kb,
    const unsigned short* __restrict__ Vtb, const float* __restrict__ biasT,
    unsigned short* __restrict__ Ob)
{
    const int bh   = blockIdx.x;      // 0..2303
    const int bwin = bh >> 3;
    const int h    = bh & 7;

    __shared__ __align__(16) unsigned short Ks[304 * 40];   // 24320 B, pitch 40 halves
    __shared__ __align__(16) unsigned short Vts[32 * 328];  // 20992 B, permuted V^T, pitch 328

    const int t    = threadIdx.x;
    const int w    = t >> 6;
    const int lane = t & 63;
    const int quad = lane >> 4;
    const int l15  = lane & 15;

    // ---- stage K with padded pitch (rows >= NWIN zeroed)
    {
        const unsigned short* Kg = Kb + (size_t)bh * (NWIN * DH);
        for (int i = t; i < 304 * 4; i += 256) {
            const int row = i >> 2, seg = i & 3;
            uint4 v = (uint4){0u, 0u, 0u, 0u};
            if (row < NWIN) v = *(const uint4*)(Kg + row * 32 + seg * 8);
            *(uint4*)(Ks + row * 40 + seg * 8) = v;
        }
    }
    // ---- stage V^T in permuted key order, zero pad (8B chunks)
    {
        const unsigned short* Vg = Vtb + (size_t)bh * (DH * NWIN);
        for (int i = t; i < 32 * 80; i += 256) {
            const int d = i / 80, c = i - d * 80;     // c: 8B chunk = 4 positions
            const int kt = c >> 3, qd = (c >> 1) & 3, hf = c & 1;
            const int kb = kt * 32 + hf * 16 + qd * 4;  // source key base
            unsigned int u0 = 0u, u1 = 0u;
            if (kb + 3 < NWIN) {
                u0 = *(const unsigned int*)(Vg + d * NWIN + kb);
                u1 = *(const unsigned int*)(Vg + d * NWIN + kb + 2);
            } else if (kb < NWIN) {   // boundary chunk (keys 292,293)
                unsigned short r0 = Vg[d * NWIN + kb];
                unsigned short r1 = (kb + 1 < NWIN) ? Vg[d * NWIN + kb + 1] : (unsigned short)0;
                unsigned short r2 = (kb + 2 < NWIN) ? Vg[d * NWIN + kb + 2] : (unsigned short)0;
                u0 = (unsigned int)r0 | ((unsigned int)r1 << 16);
                u1 = (unsigned int)r2;
            }
            unsigned int* dst = (unsigned int*)(Vts + d * 328 + c * 4);
            dst[0] = u0; dst[1] = u1;
        }
    }
    __syncthreads();

    const float SL2E = 0.25503486f;   // (1/sqrt(32)) * log2(e)
    const unsigned short* Qg = Qb + (size_t)bh * (NWIN * DH);
    const float* biasH = biasT + (size_t)h * QPAD * QPAD;
    const short8 ones = (short8){0x3F80,0x3F80,0x3F80,0x3F80,0x3F80,0x3F80,0x3F80,0x3F80};

#pragma unroll
    for (int r5 = 0; r5 < 5; ++r5) {
        const int it = 4 * r5 + w;
        if (it < 19) {
            // ---- Q fragment for this query tile (B-operand; zero pad rows)
            short8 qf;
            const int qrow = it * 16 + l15;
            if (qrow < NWIN) qf = *(const short8*)(Qg + qrow * DH + quad * 8);
            else             qf = (short8){0,0,0,0,0,0,0,0};

            const float* bb = biasH + (size_t)qrow * QPAD;  // bias row for query qrow

            // ---- S^T = K Q^T : D(row=key quad*4+reg, col=query l15)
            f32x4 S[19];
#pragma unroll
            for (int jt = 0; jt < 19; ++jt) {
                const short8 kf = *(const short8*)(Ks + (jt * 16 + l15) * 40 + quad * 8);
                S[jt] = __builtin_amdgcn_mfma_f32_16x16x32_bf16(kf, qf, (f32x4){0.f,0.f,0.f,0.f}, 0, 0, 0);
            }

            // ---- p = exp2(s*SL2E + bias'); bias from dense L2-resident table
            unsigned pk0[20], pk1[20];
            pk0[19] = 0u; pk1[19] = 0u;
#pragma unroll
            for (int jt = 0; jt < 19; ++jt) {
                const f32x4 b4 = *(const f32x4*)(bb + jt * 16 + quad * 4);
                float p0 = exp2f(fmaf(S[jt][0], SL2E, b4[0]));
                float p1 = exp2f(fmaf(S[jt][1], SL2E, b4[1]));
                float p2 = exp2f(fmaf(S[jt][2], SL2E, b4[2]));
                float p3 = exp2f(fmaf(S[jt][3], SL2E, b4[3]));
                if (jt == 18) {     // mask pad keys (288 + quad*4 + r >= 294)
                    if (quad * 4 + 0 >= 6) p0 = 0.f;
                    if (quad * 4 + 1 >= 6) p1 = 0.f;
                    if (quad * 4 + 2 >= 6) p2 = 0.f;
                    if (quad * 4 + 3 >= 6) p3 = 0.f;
                }
                pk0[jt] = pk2bf(p0, p1);
                pk1[jt] = pk2bf(p2, p3);
            }

            // ---- O = P V, lsum = P 1. A-fragment is a pure register repack:
            // k-slot order p = quad*8 + half*4 + j <-> key = half*16+quad*4+j,
            // matching Vts' permuted staging. No cross-lane movement needed.
            f32x4 o0 = {0.f,0.f,0.f,0.f}, o1 = {0.f,0.f,0.f,0.f}, o2 = {0.f,0.f,0.f,0.f};
#pragma unroll
            for (int kt = 0; kt < 10; ++kt) {
                uint4 pw;
                pw.x = pk0[2 * kt];       // keys quad*4+0,1 (half 0)
                pw.y = pk1[2 * kt];       // keys quad*4+2,3 (half 0)
                pw.z = pk0[2 * kt + 1];   // keys 16+quad*4+0,1 (half 1)
                pw.w = pk1[2 * kt + 1];   // keys 16+quad*4+2,3 (half 1)
                short8 pa;
                __builtin_memcpy(&pa, &pw, 16);
                const short8 v0 = *(const short8*)(Vts + l15 * 328 + kt * 32 + quad * 8);
                const short8 v1 = *(const short8*)(Vts + (16 + l15) * 328 + kt * 32 + quad * 8);
                o0 = __builtin_amdgcn_mfma_f32_16x16x32_bf16(pa, v0, o0, 0, 0, 0);
                o1 = __builtin_amdgcn_mfma_f32_16x16x32_bf16(pa, v1, o1, 0, 0, 0);
                o2 = __builtin_amdgcn_mfma_f32_16x16x32_bf16(pa, ones, o2, 0, 0, 0);
            }

            // ---- normalize + store bf16 (row=query=quad*4+r, col d = l15 / 16+l15)
#pragma unroll
            for (int r = 0; r < 4; ++r) {
                const int rg = it * 16 + quad * 4 + r;
                if (rg < NWIN) {
                    const float inv = 1.0f / o2[r];
                    unsigned short* op = Ob + ((size_t)bwin * NWIN + rg) * DIM + h * DH;
                    op[l15]      = f2bf(o0[r] * inv);
                    op[16 + l15] = f2bf(o1[r] * inv);
                }
            }
        }
    }
}

// ---------------------------------------------------------------------------
// Kernel 3: output projection. Same double-buffered stage-ahead loop + swizzle.
// ---------------------------------------------------------------------------
__global__ __launch_bounds__(256) void gemm_out(
    const unsigned short* __restrict__ Ob, const unsigned short* __restrict__ Wot,
    float* __restrict__ out)
{
    __shared__ __align__(16) unsigned short As[2][128 * 64];
    __shared__ __align__(16) unsigned short Bs[2][128 * 64];

    const int wg = xcd_swizzle(blockIdx.x, 662 * 2);
    const int bn = wg & 1;
    const int bm = wg >> 1;
    const int tileM = bm * 128;
    const int tileN = bn * 128;

    const int t    = threadIdx.x;
    const int w    = t >> 6;
    const int lane = t & 63;
    const int quad = lane >> 4;
    const int l15  = lane & 15;
    const int wm   = w >> 1, wn = w & 1;

    const int rA = lane >> 3;
    const int kA = (lane & 7) * 8;
    const unsigned short* aBase = Ob  + ((size_t)tileM + rA) * 256 + kA;
    const unsigned short* bBase = Wot + ((size_t)tileN + rA) * 256 + kA;

    f32x4 acc[4][4] = {};

    stage_tile(aBase, bBase, As[0], Bs[0], w, 0);
    __syncthreads();
#pragma unroll
    for (int kb = 0; kb < 3; ++kb) {
        const int cur = kb & 1;
        stage_tile(aBase, bBase, As[cur ^ 1], Bs[cur ^ 1], w, (kb + 1) * 64);
        tile_mfma(As[cur], Bs[cur], wm, wn, quad, l15, acc);
        __syncthreads();
    }
    tile_mfma(As[1], Bs[1], wm, wn, quad, l15, acc);

    const int colB = tileN + wn * 64;
    const int rowB = tileM + wm * 64 + quad * 4;
#pragma unroll
    for (int mi = 0; mi < 4; ++mi) {
#pragma unroll
        for (int r = 0; r < 4; ++r) {
            const int row = rowB + mi * 16 + r;
            if (row < MROWS) {
                const int bw = row / NWIN, rw = row - bw * NWIN;
                const int bb = bw / 144,  r2 = bw - bb * 144;
                const int gxi = r2 / 12,  gyi = r2 - gxi * 12;
                const int lz = rw / 49,   r3 = rw - lz * 49;
                const int wa = r3 / 7,    wb = r3 - wa * 7;
                float* orow = out + ((((((size_t)bb * 6 + lz) * 12 + gxi) * 12 + gyi) * 7 + wa) * 7 + wb) * DIM;
#pragma unroll
                for (int ni = 0; ni < 4; ++ni)
                    orow[colB + ni * 16 + l15] = acc[mi][ni][r];
            }
        }
    }
}

// ---------------------------------------------------------------------------
extern "C" void kernel_launch(void* const* d_in, const int* in_sizes, int n_in,
                              void* d_out, int out_size, void* d_ws, size_t ws_size,
                              hipStream_t stream)
{
    const float* x          = (const float*)d_in[0];
    const float* Wq         = (const float*)d_in[1];
    const float* bq         = (const float*)d_in[2];
    const float* Wkv        = (const float*)d_in[3];
    const float* bkv        = (const float*)d_in[4];
    const float* Wout       = (const float*)d_in[5];
    const float* bias_table = (const float*)d_in[6];
    float* out = (float*)d_out;

    const size_t planePad = (size_t)MPAD * DIM;
    const size_t plane    = (size_t)MROWS * DIM;
    unsigned short* Xb  = (unsigned short*)d_ws;
    unsigned short* Qb  = Xb + planePad;
    unsigned short* Kb  = Qb + plane;
    unsigned short* Vtb = Kb + plane;
    unsigned short* Ob  = Vtb + plane;
    unsigned short* Wt  = Ob + planePad;
    unsigned short* Wot = Wt + 768 * 256;
    float*          biasT = (float*)(Wot + 256 * 256);   // 16B-aligned

    prep_x<<<MPAD / 8, 256, 0, stream>>>(x, Xb);
    prep_w<<<1024, 256, 0, stream>>>(Wq, Wkv, Wout, Wt, Wot);
    prep_bias<<<(NHEADS * QPAD * QPAD + 255) / 256, 256, 0, stream>>>(bias_table, biasT);
    gemm_qkv<<<662 * 6, 256, 0, stream>>>(Xb, Wt, bq, bkv, Qb, Kb, Vtb);
    attn_kernel<<<BWIN * NHEADS, 256, 0, stream>>>(Qb, Kb, Vtb, biasT, Ob);
    gemm_out<<<662 * 2, 256, 0, stream>>>(Ob, Wot, out);
}